// Round 5
// baseline (172.535 us; speedup 1.0000x reference)
//
#include <hip/hip_runtime.h>

#define N_ROWS 200000
#define D_IN   256
#define D_LAT  64
#define K_CL   100
#define NT     7            // 7 cluster tiles of 16 -> 112 (cols >=100 masked)
#define TPB    256

#define GRPS     3125       // row groups of 64 (4 waves x 16 rows)
#define NBLK_P1  625
#define P1_ITERS 5          // 3125 / 625

#define NS1    1750         // stream blocks in dispatch 1
#define NS2    1375         // stream blocks in dispatch 2
#define SPAIRS 16           // float4-pairs per stream thread
#define BURST  8            // pairs per burst (16 loads in flight)
#define SSTRIDE ((NS1 + NS2) * TPB)   // 800000; (NS1+NS2)*TPB*SPAIRS = 12.8e6 pairs

#define NSLOT  64

typedef __attribute__((ext_vector_type(8))) short bf16x8;
typedef __attribute__((ext_vector_type(4))) float f32x4;

__device__ __forceinline__ float rcpf(float x) { return __builtin_amdgcn_rcpf(x); }

__device__ __forceinline__ short f2bf(float f) {
    union { float f; unsigned u; } v; v.f = f;
    unsigned r = (v.u + 0x7fffu + ((v.u >> 16) & 1u)) >> 16;
    return (short)r;
}

__device__ __forceinline__ void cvt8r(float4 a, float4 b, bf16x8& o, float& sq) {
    sq = fmaf(a.x, a.x, sq); sq = fmaf(a.y, a.y, sq);
    sq = fmaf(a.z, a.z, sq); sq = fmaf(a.w, a.w, sq);
    sq = fmaf(b.x, b.x, sq); sq = fmaf(b.y, b.y, sq);
    sq = fmaf(b.z, b.z, sq); sq = fmaf(b.w, b.w, sq);
    o[0] = f2bf(a.x); o[1] = f2bf(a.y); o[2] = f2bf(a.z); o[3] = f2bf(a.w);
    o[4] = f2bf(b.x); o[5] = f2bf(b.y); o[6] = f2bf(b.z); o[7] = f2bf(b.w);
}

__device__ __forceinline__ void cvt8(const float* __restrict__ p, bf16x8& o, float& sq) {
    float4 a = *(const float4*)p;
    float4 b = *(const float4*)(p + 4);
    cvt8r(a, b, o, sq);
}

// ---- lane ids ----
#define LANE_IDS()                                                             \
    const int tid = threadIdx.x;                                               \
    const int l   = tid & 63;                                                  \
    const int w   = tid >> 6;                                                  \
    const int c16 = l & 15;                                                    \
    const int g   = l >> 4;

// ---- B fragments + ||c||^2 in-register ----
#define PROLOGUE_B()                                                           \
    bf16x8 bfrag[NT][2];                                                       \
    float  cn2v[NT];                                                           \
    _Pragma("unroll")                                                          \
    for (int t = 0; t < NT; ++t) {                                             \
        int col = t * 16 + c16;                                                \
        bool valid = col < K_CL;                                               \
        float sq = 0.f;                                                        \
        _Pragma("unroll")                                                      \
        for (int kt = 0; kt < 2; ++kt) {                                       \
            bf16x8 bf;                                                         \
            if (valid) {                                                       \
                cvt8(cen + col * D_LAT + kt * 32 + g * 8, bf, sq);             \
            } else {                                                           \
                _Pragma("unroll")                                              \
                for (int i = 0; i < 8; ++i) bf[i] = 0;                         \
            }                                                                  \
            bfrag[t][kt] = bf;                                                 \
        }                                                                      \
        sq += __shfl_xor(sq, 16);                                              \
        sq += __shfl_xor(sq, 32);                                              \
        cn2v[t] = sq;                                                          \
    }                                                                          \
    const bool v6 = (c16 < 4); /* tile 6: cols 96..111, valid < 100 */

// ---- issue this group's enc loads (raw float4, latency overlappable) ----
#define GROUP_LOADS(grp)                                                       \
    const int rowbase = (grp) * 64 + w * 16;                                   \
    const float* arow = enc + (size_t)(rowbase + c16) * D_LAT + g * 8;         \
    float4 la0 = *(const float4*)(arow);                                       \
    float4 la1 = *(const float4*)(arow + 4);                                   \
    float4 la2 = *(const float4*)(arow + 32);                                  \
    float4 la3 = *(const float4*)(arow + 36);

// ---- convert, MFMA dot, q + row-sums -> qv[NT][4], rs[4] ----
#define GROUP_COMPUTE()                                                        \
    float en2p = 0.f;                                                          \
    bf16x8 afrag0, afrag1;                                                     \
    cvt8r(la0, la1, afrag0, en2p);                                             \
    cvt8r(la2, la3, afrag1, en2p);                                             \
    en2p += __shfl_xor(en2p, 16);                                              \
    en2p += __shfl_xor(en2p, 32);                                              \
    f32x4 acc[NT];                                                             \
    _Pragma("unroll")                                                          \
    for (int t = 0; t < NT; ++t) {                                             \
        acc[t][0] = 0.f; acc[t][1] = 0.f; acc[t][2] = 0.f; acc[t][3] = 0.f;    \
    }                                                                          \
    _Pragma("unroll")                                                          \
    for (int t = 0; t < NT; ++t)                                               \
        acc[t] = __builtin_amdgcn_mfma_f32_16x16x32_bf16(afrag0, bfrag[t][0], acc[t], 0, 0, 0); \
    _Pragma("unroll")                                                          \
    for (int t = 0; t < NT; ++t)                                               \
        acc[t] = __builtin_amdgcn_mfma_f32_16x16x32_bf16(afrag1, bfrag[t][1], acc[t], 0, 0, 0); \
    float en2r[4];                                                             \
    _Pragma("unroll")                                                          \
    for (int r = 0; r < 4; ++r) en2r[r] = __shfl(en2p, g * 4 + r);             \
    float qv[NT][4];                                                           \
    float rs[4] = {0.f, 0.f, 0.f, 0.f};                                        \
    _Pragma("unroll")                                                          \
    for (int t = 0; t < NT; ++t) {                                             \
        _Pragma("unroll")                                                      \
        for (int r = 0; r < 4; ++r) {                                          \
            float d2 = en2r[r] + cn2v[t] - 2.f * acc[t][r];                    \
            float q = rcpf(1.f + fmaxf(d2, 0.f));                              \
            if (t == 6 && !v6) q = 0.f;                                        \
            qv[t][r] = q; rs[r] += q;                                          \
        }                                                                      \
    }                                                                          \
    _Pragma("unroll")                                                          \
    for (int r = 0; r < 4; ++r) {                                              \
        rs[r] += __shfl_xor(rs[r], 1); rs[r] += __shfl_xor(rs[r], 2);          \
        rs[r] += __shfl_xor(rs[r], 4); rs[r] += __shfl_xor(rs[r], 8);          \
        rs[r] = rcpf(rs[r]);                                                   \
    }

// ---- decoder-loss stream: 16 pairs/thread, 2 bursts of 8 (16 loads in flight) ----
__device__ __forceinline__ void dec_stream(const f32x4* __restrict__ X,
                                           const f32x4* __restrict__ Dec,
                                           double* __restrict__ slots, int v) {
    int idx = v * TPB + (int)threadIdx.x;
    float local = 0.f;
#pragma unroll 1
    for (int o = 0; o < SPAIRS / BURST; ++o) {
        f32x4 a[BURST], b[BURST];
#pragma unroll
        for (int u = 0; u < BURST; ++u) {
            a[u] = __builtin_nontemporal_load(X + idx + u * SSTRIDE);
            b[u] = __builtin_nontemporal_load(Dec + idx + u * SSTRIDE);
        }
#pragma unroll
        for (int u = 0; u < BURST; ++u) {
            f32x4 d = a[u] - b[u];
            local = fmaf(d.x, d.x, local); local = fmaf(d.y, d.y, local);
            local = fmaf(d.z, d.z, local); local = fmaf(d.w, d.w, local);
        }
        idx += BURST * SSTRIDE;
    }
    __shared__ float red[TPB];
    red[threadIdx.x] = local;
    __syncthreads();
    for (int off = TPB / 2; off > 0; off >>= 1) {
        if (threadIdx.x < off) red[threadIdx.x] += red[threadIdx.x + off];
        __syncthreads();
    }
    if (threadIdx.x == 0) atomicAdd(&slots[v & (NSLOT - 1)], (double)red[0]);
}

// ---- dispatch 1: stream blocks [0,NS1) + pass1 blocks [NS1, NS1+625) ----
__global__ void __launch_bounds__(TPB) k_d1(const f32x4* __restrict__ X,
                                            const f32x4* __restrict__ Xdec,
                                            const float* __restrict__ enc,
                                            const float* __restrict__ cen,
                                            double* __restrict__ dec_slots,
                                            float* __restrict__ fg) {
    if (blockIdx.x < NS1) {
        dec_stream(X, Xdec, dec_slots, blockIdx.x);
        return;
    }
    LANE_IDS();
    PROLOGUE_B();
    float facc[NT];
#pragma unroll
    for (int t = 0; t < NT; ++t) facc[t] = 0.f;
    const int p1id = blockIdx.x - NS1;
#pragma unroll 1
    for (int j = 0; j < P1_ITERS; ++j) {
        const int grpv = p1id + j * NBLK_P1;
        GROUP_LOADS(grpv);
        GROUP_COMPUTE();
#pragma unroll
        for (int t = 0; t < NT; ++t) {
            float a = 0.f;
#pragma unroll
            for (int r = 0; r < 4; ++r) a = fmaf(qv[t][r], rs[r], a);
            facc[t] += a;
        }
    }
    __shared__ float f_s[K_CL];
    for (int i = tid; i < K_CL; i += TPB) f_s[i] = 0.f;
    __syncthreads();
#pragma unroll
    for (int t = 0; t < NT; ++t) {
        float a = facc[t];
        a += __shfl_xor(a, 16);
        a += __shfl_xor(a, 32);
        int col = t * 16 + c16;
        if (g == 0 && col < K_CL) atomicAdd(&f_s[col], a);
    }
    __syncthreads();
    for (int i = tid; i < K_CL; i += TPB) atomicAdd(&fg[i], f_s[i]);
}

// ---- dispatch 2: stream blocks [0,NS2) + pass2 blocks (one group each) ----
__global__ void __launch_bounds__(TPB) k_d2(const f32x4* __restrict__ X,
                                            const f32x4* __restrict__ Xdec,
                                            const float* __restrict__ enc,
                                            const float* __restrict__ cen,
                                            const float* __restrict__ fg,
                                            double* __restrict__ dec_slots,
                                            double* __restrict__ kl_slots) {
    if (blockIdx.x < NS2) {
        dec_stream(X, Xdec, dec_slots, NS1 + blockIdx.x);
        return;
    }
    LANE_IDS();
    const int grpv = blockIdx.x - NS2;
    GROUP_LOADS(grpv);          // issue enc loads first; latency hides under prologue
    PROLOGUE_B();
    float lfv[NT], rfv[NT];
#pragma unroll
    for (int t = 0; t < NT; ++t) {
        int col = t * 16 + c16;
        if (col < K_CL) {
            float fv = fg[col];
            lfv[t] = __logf(fv);
            rfv[t] = rcpf(fv);
        } else { lfv[t] = 0.f; rfv[t] = 0.f; }
    }
    GROUP_COMPUTE();
    float tac[4] = {0.f, 0.f, 0.f, 0.f};
    float Ap[4]  = {0.f, 0.f, 0.f, 0.f};
    float Bp[4]  = {0.f, 0.f, 0.f, 0.f};
#pragma unroll
    for (int t = 0; t < NT; ++t) {
#pragma unroll
        for (int r = 0; r < 4; ++r) {
            if (t == 6 && !v6) continue;      // masked col: q==0, avoid log(0)
            float q = qv[t][r] * rs[r];
            float pu = q * q * rfv[t];
            tac[r] += pu;
            Ap[r] = fmaf(pu, __logf(q), Ap[r]);
            Bp[r] = fmaf(pu, lfv[t], Bp[r]);
        }
    }
#pragma unroll
    for (int r = 0; r < 4; ++r) {
        tac[r] += __shfl_xor(tac[r], 1); tac[r] += __shfl_xor(tac[r], 2);
        tac[r] += __shfl_xor(tac[r], 4); tac[r] += __shfl_xor(tac[r], 8);
        Ap[r]  += __shfl_xor(Ap[r], 1);  Ap[r]  += __shfl_xor(Ap[r], 2);
        Ap[r]  += __shfl_xor(Ap[r], 4);  Ap[r]  += __shfl_xor(Ap[r], 8);
        Bp[r]  += __shfl_xor(Bp[r], 1);  Bp[r]  += __shfl_xor(Bp[r], 2);
        Bp[r]  += __shfl_xor(Bp[r], 4);  Bp[r]  += __shfl_xor(Bp[r], 8);
    }
    float kl_local = 0.f;
    if (c16 == 0) {
#pragma unroll
        for (int r = 0; r < 4; ++r)
            kl_local += (Ap[r] - Bp[r]) * rcpf(tac[r]) - __logf(tac[r]);
    }
    __shared__ float red[TPB];
    red[tid] = kl_local;
    __syncthreads();
    for (int off = TPB / 2; off > 0; off >>= 1) {
        if (tid < off) red[tid] += red[tid + off];
        __syncthreads();
    }
    if (tid == 0) atomicAdd(&kl_slots[grpv & (NSLOT - 1)], (double)red[0]);
}

__global__ void k_final(const double* __restrict__ dec_s,
                        const double* __restrict__ kl_s,
                        float* __restrict__ out) {
    int l = threadIdx.x;     // 64 threads = one wave
    double d = dec_s[l];
    double k = kl_s[l];
#pragma unroll
    for (int off = 32; off > 0; off >>= 1) {
        d += __shfl_xor(d, off);
        k += __shfl_xor(k, off);
    }
    if (l == 0)
        out[0] = (float)(d / ((double)N_ROWS * (double)D_IN) + 1000.0 * (k / (double)N_ROWS));
}

extern "C" void kernel_launch(void* const* d_in, const int* in_sizes, int n_in,
                              void* d_out, int out_size, void* d_ws, size_t ws_size,
                              hipStream_t stream) {
    (void)in_sizes; (void)n_in; (void)out_size; (void)ws_size;
    const float* X   = (const float*)d_in[0];
    const float* enc = (const float*)d_in[1];
    const float* dec = (const float*)d_in[2];
    const float* cen = (const float*)d_in[3];
    float* out = (float*)d_out;

    double* dec_slots = (double*)d_ws;                       // 64 doubles
    double* kl_slots  = (double*)((char*)d_ws + 512);        // 64 doubles
    float*  fg        = (float*)((char*)d_ws + 1024);        // 128 floats

    hipMemsetAsync(d_ws, 0, 1536, stream);
    k_d1<<<NS1 + NBLK_P1, TPB, 0, stream>>>(
        (const f32x4*)X, (const f32x4*)dec, enc, cen, dec_slots, fg);
    k_d2<<<NS2 + GRPS, TPB, 0, stream>>>(
        (const f32x4*)X, (const f32x4*)dec, enc, cen, fg, dec_slots, kl_slots);
    k_final<<<1, 64, 0, stream>>>(dec_slots, kl_slots, out);
}

// Round 6
// 135.658 us; speedup vs baseline: 1.2718x; 1.2718x over previous
//
#include <hip/hip_runtime.h>

#define N_ROWS 200000
#define D_IN   256
#define D_LAT  64
#define K_CL   100
#define NT     7            // 7 cluster tiles of 16 -> 112 (cols >=100 masked)
#define TPB    256

#define GRPS   3125         // row groups of 64 (4 waves x 16 rows)
#define NMF    625          // MFMA blocks per dispatch
#define GPB    5            // groups per MFMA block (3125/625)

#define NS1    1563         // stream blocks in dispatch 1
#define NS2    1562         // stream blocks in dispatch 2 (NS1+NS2 = 3125)
#define SPAIRS 16           // float4 indices per stream thread
#define BURST  8            // per burst: 8 X + 8 Dec float4 loads in flight
#define SSTRIDE ((NS1 + NS2) * TPB)   // 800000; *SPAIRS = 12.8e6 float4s

#define NSLOT  64

typedef __attribute__((ext_vector_type(8))) short bf16x8;
typedef __attribute__((ext_vector_type(4))) float f32x4;

__device__ __forceinline__ float rcpf(float x) { return __builtin_amdgcn_rcpf(x); }

__device__ __forceinline__ short f2bf(float f) {
    union { float f; unsigned u; } v; v.f = f;
    unsigned r = (v.u + 0x7fffu + ((v.u >> 16) & 1u)) >> 16;
    return (short)r;
}

__device__ __forceinline__ void cvt8r(float4 a, float4 b, bf16x8& o, float& sq) {
    sq = fmaf(a.x, a.x, sq); sq = fmaf(a.y, a.y, sq);
    sq = fmaf(a.z, a.z, sq); sq = fmaf(a.w, a.w, sq);
    sq = fmaf(b.x, b.x, sq); sq = fmaf(b.y, b.y, sq);
    sq = fmaf(b.z, b.z, sq); sq = fmaf(b.w, b.w, sq);
    o[0] = f2bf(a.x); o[1] = f2bf(a.y); o[2] = f2bf(a.z); o[3] = f2bf(a.w);
    o[4] = f2bf(b.x); o[5] = f2bf(b.y); o[6] = f2bf(b.z); o[7] = f2bf(b.w);
}

__device__ __forceinline__ void cvt8(const float* __restrict__ p, bf16x8& o, float& sq) {
    float4 a = *(const float4*)p;
    float4 b = *(const float4*)(p + 4);
    cvt8r(a, b, o, sq);
}

// ---- lane ids ----
#define LANE_IDS()                                                             \
    const int tid = threadIdx.x;                                               \
    const int l   = tid & 63;                                                  \
    const int w   = tid >> 6;                                                  \
    const int c16 = l & 15;                                                    \
    const int g   = l >> 4;

// ---- B fragments + ||c||^2 in-register ----
#define PROLOGUE_B()                                                           \
    bf16x8 bfrag[NT][2];                                                       \
    float  cn2v[NT];                                                           \
    _Pragma("unroll")                                                          \
    for (int t = 0; t < NT; ++t) {                                             \
        int col = t * 16 + c16;                                                \
        bool valid = col < K_CL;                                               \
        float sq = 0.f;                                                        \
        _Pragma("unroll")                                                      \
        for (int kt = 0; kt < 2; ++kt) {                                       \
            bf16x8 bf;                                                         \
            if (valid) {                                                       \
                cvt8(cen + col * D_LAT + kt * 32 + g * 8, bf, sq);             \
            } else {                                                           \
                _Pragma("unroll")                                              \
                for (int i = 0; i < 8; ++i) bf[i] = 0;                         \
            }                                                                  \
            bfrag[t][kt] = bf;                                                 \
        }                                                                      \
        sq += __shfl_xor(sq, 16);                                              \
        sq += __shfl_xor(sq, 32);                                              \
        cn2v[t] = sq;                                                          \
    }                                                                          \
    const bool v6 = (c16 < 4); /* tile 6: cols 96..111, valid < 100 */

// ---- issue one group's enc loads into a named float4[4] ----
#define LOADS4(grp, A)                                                         \
    {                                                                          \
        const int rowbase_ = (grp) * 64 + w * 16;                              \
        const float* arow_ = enc + (size_t)(rowbase_ + c16) * D_LAT + g * 8;   \
        A[0] = *(const float4*)(arow_);                                        \
        A[1] = *(const float4*)(arow_ + 4);                                    \
        A[2] = *(const float4*)(arow_ + 32);                                   \
        A[3] = *(const float4*)(arow_ + 36);                                   \
    }

// ---- convert, MFMA dot, q + row-sums -> qv[NT][4], rs[4] (reads A[0..3]) ----
#define GROUP_COMPUTE_FROM(A)                                                  \
    float en2p = 0.f;                                                          \
    bf16x8 afrag0, afrag1;                                                     \
    cvt8r(A[0], A[1], afrag0, en2p);                                           \
    cvt8r(A[2], A[3], afrag1, en2p);                                           \
    en2p += __shfl_xor(en2p, 16);                                              \
    en2p += __shfl_xor(en2p, 32);                                              \
    f32x4 acc[NT];                                                             \
    _Pragma("unroll")                                                          \
    for (int t = 0; t < NT; ++t) {                                             \
        acc[t][0] = 0.f; acc[t][1] = 0.f; acc[t][2] = 0.f; acc[t][3] = 0.f;    \
    }                                                                          \
    _Pragma("unroll")                                                          \
    for (int t = 0; t < NT; ++t)                                               \
        acc[t] = __builtin_amdgcn_mfma_f32_16x16x32_bf16(afrag0, bfrag[t][0], acc[t], 0, 0, 0); \
    _Pragma("unroll")                                                          \
    for (int t = 0; t < NT; ++t)                                               \
        acc[t] = __builtin_amdgcn_mfma_f32_16x16x32_bf16(afrag1, bfrag[t][1], acc[t], 0, 0, 0); \
    float en2r[4];                                                             \
    _Pragma("unroll")                                                          \
    for (int r = 0; r < 4; ++r) en2r[r] = __shfl(en2p, g * 4 + r);             \
    float qv[NT][4];                                                           \
    float rs[4] = {0.f, 0.f, 0.f, 0.f};                                        \
    _Pragma("unroll")                                                          \
    for (int t = 0; t < NT; ++t) {                                             \
        _Pragma("unroll")                                                      \
        for (int r = 0; r < 4; ++r) {                                          \
            float d2 = en2r[r] + cn2v[t] - 2.f * acc[t][r];                    \
            float q = rcpf(1.f + fmaxf(d2, 0.f));                              \
            if (t == 6 && !v6) q = 0.f;                                        \
            qv[t][r] = q; rs[r] += q;                                          \
        }                                                                      \
    }                                                                          \
    _Pragma("unroll")                                                          \
    for (int r = 0; r < 4; ++r) {                                              \
        rs[r] += __shfl_xor(rs[r], 1); rs[r] += __shfl_xor(rs[r], 2);          \
        rs[r] += __shfl_xor(rs[r], 4); rs[r] += __shfl_xor(rs[r], 8);          \
        rs[r] = rcpf(rs[r]);                                                   \
    }

// ---- decoder-loss stream: 16 float4s/thread, 2 bursts of 8 ----
__device__ __forceinline__ void dec_stream(const f32x4* __restrict__ X,
                                           const f32x4* __restrict__ Dec,
                                           double* __restrict__ slots, int v) {
    int idx = v * TPB + (int)threadIdx.x;
    float local = 0.f;
#pragma unroll 1
    for (int o = 0; o < SPAIRS / BURST; ++o) {
        f32x4 a[BURST], b[BURST];
#pragma unroll
        for (int u = 0; u < BURST; ++u) {
            a[u] = __builtin_nontemporal_load(X + idx + u * SSTRIDE);
            b[u] = __builtin_nontemporal_load(Dec + idx + u * SSTRIDE);
        }
#pragma unroll
        for (int u = 0; u < BURST; ++u) {
            f32x4 d = a[u] - b[u];
            local = fmaf(d.x, d.x, local); local = fmaf(d.y, d.y, local);
            local = fmaf(d.z, d.z, local); local = fmaf(d.w, d.w, local);
        }
        idx += BURST * SSTRIDE;
    }
    __shared__ float red[TPB];
    red[threadIdx.x] = local;
    __syncthreads();
    for (int off = TPB / 2; off > 0; off >>= 1) {
        if (threadIdx.x < off) red[threadIdx.x] += red[threadIdx.x + off];
        __syncthreads();
    }
    if (threadIdx.x == 0) atomicAdd(&slots[v & (NSLOT - 1)], (double)red[0]);
}

// ---- dispatch 1: MFMA pass1 blocks [0,625) + stream blocks [625, 625+NS1) ----
__global__ void __launch_bounds__(TPB) k_d1(const f32x4* __restrict__ X,
                                            const f32x4* __restrict__ Xdec,
                                            const float* __restrict__ enc,
                                            const float* __restrict__ cen,
                                            double* __restrict__ dec_slots,
                                            float* __restrict__ fg) {
    if (blockIdx.x >= NMF) {
        dec_stream(X, Xdec, dec_slots, blockIdx.x - NMF);
        return;
    }
    LANE_IDS();
    const int p1id = blockIdx.x;
    float4 abuf[2][4];
    LOADS4(p1id, abuf[0]);
    PROLOGUE_B();
    float facc[NT];
#pragma unroll
    for (int t = 0; t < NT; ++t) facc[t] = 0.f;
#pragma unroll
    for (int j = 0; j < GPB; ++j) {
        if (j + 1 < GPB) LOADS4(p1id + (j + 1) * NMF, abuf[(j + 1) & 1]);
        GROUP_COMPUTE_FROM(abuf[j & 1]);
#pragma unroll
        for (int t = 0; t < NT; ++t) {
            float a = 0.f;
#pragma unroll
            for (int r = 0; r < 4; ++r) a = fmaf(qv[t][r], rs[r], a);
            facc[t] += a;
        }
    }
    __shared__ float f_s[K_CL];
    for (int i = tid; i < K_CL; i += TPB) f_s[i] = 0.f;
    __syncthreads();
#pragma unroll
    for (int t = 0; t < NT; ++t) {
        float a = facc[t];
        a += __shfl_xor(a, 16);
        a += __shfl_xor(a, 32);
        int col = t * 16 + c16;
        if (g == 0 && col < K_CL) atomicAdd(&f_s[col], a);
    }
    __syncthreads();
    for (int i = tid; i < K_CL; i += TPB) atomicAdd(&fg[i], f_s[i]);
}

// ---- dispatch 2: MFMA pass2 blocks [0,625) + stream blocks [625, 625+NS2) ----
__global__ void __launch_bounds__(TPB) k_d2(const f32x4* __restrict__ X,
                                            const f32x4* __restrict__ Xdec,
                                            const float* __restrict__ enc,
                                            const float* __restrict__ cen,
                                            const float* __restrict__ fg,
                                            double* __restrict__ dec_slots,
                                            double* __restrict__ kl_slots) {
    if (blockIdx.x >= NMF) {
        dec_stream(X, Xdec, dec_slots, NS1 + blockIdx.x - NMF);
        return;
    }
    LANE_IDS();
    const int p2id = blockIdx.x;
    float4 abuf[2][4];
    LOADS4(p2id, abuf[0]);
    PROLOGUE_B();
    float lfv[NT], rfv[NT];
#pragma unroll
    for (int t = 0; t < NT; ++t) {
        int col = t * 16 + c16;
        if (col < K_CL) {
            float fv = fg[col];
            lfv[t] = __logf(fv);
            rfv[t] = rcpf(fv);
        } else { lfv[t] = 0.f; rfv[t] = 0.f; }
    }
    float kl_local = 0.f;
#pragma unroll
    for (int j = 0; j < GPB; ++j) {
        if (j + 1 < GPB) LOADS4(p2id + (j + 1) * NMF, abuf[(j + 1) & 1]);
        GROUP_COMPUTE_FROM(abuf[j & 1]);
        float tac[4] = {0.f, 0.f, 0.f, 0.f};
        float Ap[4]  = {0.f, 0.f, 0.f, 0.f};
        float Bp[4]  = {0.f, 0.f, 0.f, 0.f};
#pragma unroll
        for (int t = 0; t < NT; ++t) {
#pragma unroll
            for (int r = 0; r < 4; ++r) {
                if (t == 6 && !v6) continue;      // masked col: q==0, avoid log(0)
                float q = qv[t][r] * rs[r];
                float pu = q * q * rfv[t];
                tac[r] += pu;
                Ap[r] = fmaf(pu, __logf(q), Ap[r]);
                Bp[r] = fmaf(pu, lfv[t], Bp[r]);
            }
        }
#pragma unroll
        for (int r = 0; r < 4; ++r) {
            tac[r] += __shfl_xor(tac[r], 1); tac[r] += __shfl_xor(tac[r], 2);
            tac[r] += __shfl_xor(tac[r], 4); tac[r] += __shfl_xor(tac[r], 8);
            Ap[r]  += __shfl_xor(Ap[r], 1);  Ap[r]  += __shfl_xor(Ap[r], 2);
            Ap[r]  += __shfl_xor(Ap[r], 4);  Ap[r]  += __shfl_xor(Ap[r], 8);
            Bp[r]  += __shfl_xor(Bp[r], 1);  Bp[r]  += __shfl_xor(Bp[r], 2);
            Bp[r]  += __shfl_xor(Bp[r], 4);  Bp[r]  += __shfl_xor(Bp[r], 8);
        }
        if (c16 == 0) {
#pragma unroll
            for (int r = 0; r < 4; ++r)
                kl_local += (Ap[r] - Bp[r]) * rcpf(tac[r]) - __logf(tac[r]);
        }
    }
    __shared__ float red[TPB];
    red[tid] = kl_local;
    __syncthreads();
    for (int off = TPB / 2; off > 0; off >>= 1) {
        if (tid < off) red[tid] += red[tid + off];
        __syncthreads();
    }
    if (tid == 0) atomicAdd(&kl_slots[p2id & (NSLOT - 1)], (double)red[0]);
}

__global__ void k_final(const double* __restrict__ dec_s,
                        const double* __restrict__ kl_s,
                        float* __restrict__ out) {
    int l = threadIdx.x;     // 64 threads = one wave
    double d = dec_s[l];
    double k = kl_s[l];
#pragma unroll
    for (int off = 32; off > 0; off >>= 1) {
        d += __shfl_xor(d, off);
        k += __shfl_xor(k, off);
    }
    if (l == 0)
        out[0] = (float)(d / ((double)N_ROWS * (double)D_IN) + 1000.0 * (k / (double)N_ROWS));
}

extern "C" void kernel_launch(void* const* d_in, const int* in_sizes, int n_in,
                              void* d_out, int out_size, void* d_ws, size_t ws_size,
                              hipStream_t stream) {
    (void)in_sizes; (void)n_in; (void)out_size; (void)ws_size;
    const float* X   = (const float*)d_in[0];
    const float* enc = (const float*)d_in[1];
    const float* dec = (const float*)d_in[2];
    const float* cen = (const float*)d_in[3];
    float* out = (float*)d_out;

    double* dec_slots = (double*)d_ws;                       // 64 doubles
    double* kl_slots  = (double*)((char*)d_ws + 512);        // 64 doubles
    float*  fg        = (float*)((char*)d_ws + 1024);        // 128 floats

    hipMemsetAsync(d_ws, 0, 1536, stream);
    k_d1<<<NMF + NS1, TPB, 0, stream>>>(
        (const f32x4*)X, (const f32x4*)dec, enc, cen, dec_slots, fg);
    k_d2<<<NMF + NS2, TPB, 0, stream>>>(
        (const f32x4*)X, (const f32x4*)dec, enc, cen, fg, dec_slots, kl_slots);
    k_final<<<1, 64, 0, stream>>>(dec_slots, kl_slots, out);
}

// Round 7
// 133.870 us; speedup vs baseline: 1.2888x; 1.0134x over previous
//
#include <hip/hip_runtime.h>

#define N_ROWS 200000
#define D_IN   256
#define D_LAT  64
#define K_CL   100
#define NT     7            // 7 cluster tiles of 16 -> 112 (cols >=100 masked)
#define TPB    256

#define GRPS   3125         // row groups of 64 (4 waves x 16 rows)
#define NMF    625          // MFMA blocks per dispatch
#define GPB    5            // groups per MFMA block (3125/625)

// stream geometry: 12.8e6 float4s per array = 6250 chunks of 2048 (32 KB/array)
#define SCHUNKS   6250
#define SC_HALF   3125      // chunks per dispatch
#define NSTR      512       // persistent stream blocks per dispatch
#define NSLOT     64

typedef __attribute__((ext_vector_type(8))) short bf16x8;
typedef __attribute__((ext_vector_type(4))) float f32x4;

__device__ __forceinline__ float rcpf(float x) { return __builtin_amdgcn_rcpf(x); }

__device__ __forceinline__ short f2bf(float f) {
    union { float f; unsigned u; } v; v.f = f;
    unsigned r = (v.u + 0x7fffu + ((v.u >> 16) & 1u)) >> 16;
    return (short)r;
}

__device__ __forceinline__ void cvt8r(float4 a, float4 b, bf16x8& o, float& sq) {
    sq = fmaf(a.x, a.x, sq); sq = fmaf(a.y, a.y, sq);
    sq = fmaf(a.z, a.z, sq); sq = fmaf(a.w, a.w, sq);
    sq = fmaf(b.x, b.x, sq); sq = fmaf(b.y, b.y, sq);
    sq = fmaf(b.z, b.z, sq); sq = fmaf(b.w, b.w, sq);
    o[0] = f2bf(a.x); o[1] = f2bf(a.y); o[2] = f2bf(a.z); o[3] = f2bf(a.w);
    o[4] = f2bf(b.x); o[5] = f2bf(b.y); o[6] = f2bf(b.z); o[7] = f2bf(b.w);
}

__device__ __forceinline__ void cvt8(const float* __restrict__ p, bf16x8& o, float& sq) {
    float4 a = *(const float4*)p;
    float4 b = *(const float4*)(p + 4);
    cvt8r(a, b, o, sq);
}

// ---- lane ids ----
#define LANE_IDS()                                                             \
    const int tid = threadIdx.x;                                               \
    const int l   = tid & 63;                                                  \
    const int w   = tid >> 6;                                                  \
    const int c16 = l & 15;                                                    \
    const int g   = l >> 4;

// ---- B fragments + ||c||^2 in-register ----
#define PROLOGUE_B()                                                           \
    bf16x8 bfrag[NT][2];                                                       \
    float  cn2v[NT];                                                           \
    _Pragma("unroll")                                                          \
    for (int t = 0; t < NT; ++t) {                                             \
        int col = t * 16 + c16;                                                \
        bool valid = col < K_CL;                                               \
        float sq = 0.f;                                                        \
        _Pragma("unroll")                                                      \
        for (int kt = 0; kt < 2; ++kt) {                                       \
            bf16x8 bf;                                                         \
            if (valid) {                                                       \
                cvt8(cen + col * D_LAT + kt * 32 + g * 8, bf, sq);             \
            } else {                                                           \
                _Pragma("unroll")                                              \
                for (int i = 0; i < 8; ++i) bf[i] = 0;                         \
            }                                                                  \
            bfrag[t][kt] = bf;                                                 \
        }                                                                      \
        sq += __shfl_xor(sq, 16);                                              \
        sq += __shfl_xor(sq, 32);                                              \
        cn2v[t] = sq;                                                          \
    }                                                                          \
    const bool v6 = (c16 < 4); /* tile 6: cols 96..111, valid < 100 */

// ---- issue one group's enc loads into a named float4[4] ----
#define LOADS4(grp, A)                                                         \
    {                                                                          \
        const int rowbase_ = (grp) * 64 + w * 16;                              \
        const float* arow_ = enc + (size_t)(rowbase_ + c16) * D_LAT + g * 8;   \
        A[0] = *(const float4*)(arow_);                                        \
        A[1] = *(const float4*)(arow_ + 4);                                    \
        A[2] = *(const float4*)(arow_ + 32);                                   \
        A[3] = *(const float4*)(arow_ + 36);                                   \
    }

// ---- convert, MFMA dot, q + row-sums -> qv[NT][4], rs[4] (reads A[0..3]) ----
#define GROUP_COMPUTE_FROM(A)                                                  \
    float en2p = 0.f;                                                          \
    bf16x8 afrag0, afrag1;                                                     \
    cvt8r(A[0], A[1], afrag0, en2p);                                           \
    cvt8r(A[2], A[3], afrag1, en2p);                                           \
    en2p += __shfl_xor(en2p, 16);                                              \
    en2p += __shfl_xor(en2p, 32);                                              \
    f32x4 acc[NT];                                                             \
    _Pragma("unroll")                                                          \
    for (int t = 0; t < NT; ++t) {                                             \
        acc[t][0] = 0.f; acc[t][1] = 0.f; acc[t][2] = 0.f; acc[t][3] = 0.f;    \
    }                                                                          \
    _Pragma("unroll")                                                          \
    for (int t = 0; t < NT; ++t)                                               \
        acc[t] = __builtin_amdgcn_mfma_f32_16x16x32_bf16(afrag0, bfrag[t][0], acc[t], 0, 0, 0); \
    _Pragma("unroll")                                                          \
    for (int t = 0; t < NT; ++t)                                               \
        acc[t] = __builtin_amdgcn_mfma_f32_16x16x32_bf16(afrag1, bfrag[t][1], acc[t], 0, 0, 0); \
    float en2r[4];                                                             \
    _Pragma("unroll")                                                          \
    for (int r = 0; r < 4; ++r) en2r[r] = __shfl(en2p, g * 4 + r);             \
    float qv[NT][4];                                                           \
    float rs[4] = {0.f, 0.f, 0.f, 0.f};                                        \
    _Pragma("unroll")                                                          \
    for (int t = 0; t < NT; ++t) {                                             \
        _Pragma("unroll")                                                      \
        for (int r = 0; r < 4; ++r) {                                          \
            float d2 = en2r[r] + cn2v[t] - 2.f * acc[t][r];                    \
            float q = rcpf(1.f + fmaxf(d2, 0.f));                              \
            if (t == 6 && !v6) q = 0.f;                                        \
            qv[t][r] = q; rs[r] += q;                                          \
        }                                                                      \
    }                                                                          \
    _Pragma("unroll")                                                          \
    for (int r = 0; r < 4; ++r) {                                              \
        rs[r] += __shfl_xor(rs[r], 1); rs[r] += __shfl_xor(rs[r], 2);          \
        rs[r] += __shfl_xor(rs[r], 4); rs[r] += __shfl_xor(rs[r], 8);          \
        rs[r] = rcpf(rs[r]);                                                   \
    }

// ---- decoder-loss stream: persistent blocks, 16 pinned loads in flight ----
__device__ __forceinline__ void dec_stream(const f32x4* __restrict__ X,
                                           const f32x4* __restrict__ Dec,
                                           double* __restrict__ slots,
                                           int sid, int cbase) {
    float local = 0.f;
#pragma unroll 1
    for (int c = sid; c < SC_HALF; c += NSTR) {
        const int idx = (cbase + c) * 2048 + (int)threadIdx.x;
        f32x4 a[8], b[8];
#pragma unroll
        for (int u = 0; u < 8; ++u)
            a[u] = __builtin_nontemporal_load(X + idx + u * 256);
#pragma unroll
        for (int u = 0; u < 8; ++u)
            b[u] = __builtin_nontemporal_load(Dec + idx + u * 256);
        __builtin_amdgcn_sched_barrier(0);   // pin: all 16 loads issued before use
#pragma unroll
        for (int u = 0; u < 8; ++u) {
            f32x4 d = a[u] - b[u];
            local = fmaf(d.x, d.x, local); local = fmaf(d.y, d.y, local);
            local = fmaf(d.z, d.z, local); local = fmaf(d.w, d.w, local);
        }
    }
    __shared__ float red[TPB];
    red[threadIdx.x] = local;
    __syncthreads();
    for (int off = TPB / 2; off > 0; off >>= 1) {
        if (threadIdx.x < off) red[threadIdx.x] += red[threadIdx.x + off];
        __syncthreads();
    }
    if (threadIdx.x == 0) atomicAdd(&slots[sid & (NSLOT - 1)], (double)red[0]);
}

// ---- dispatch 1: pass1 blocks [0,625) + persistent stream blocks [625, 625+NSTR) ----
__global__ void __launch_bounds__(TPB) k_d1(const f32x4* __restrict__ X,
                                            const f32x4* __restrict__ Xdec,
                                            const float* __restrict__ enc,
                                            const float* __restrict__ cen,
                                            double* __restrict__ dec_slots,
                                            float* __restrict__ fg) {
    if (blockIdx.x >= NMF) {
        dec_stream(X, Xdec, dec_slots, blockIdx.x - NMF, 0);
        return;
    }
    LANE_IDS();
    const int p1id = blockIdx.x;
    float4 abuf[2][4];
    LOADS4(p1id, abuf[0]);
    PROLOGUE_B();
    float facc[NT];
#pragma unroll
    for (int t = 0; t < NT; ++t) facc[t] = 0.f;
#pragma unroll
    for (int j = 0; j < GPB; ++j) {
        if (j + 1 < GPB) LOADS4(p1id + (j + 1) * NMF, abuf[(j + 1) & 1]);
        GROUP_COMPUTE_FROM(abuf[j & 1]);
#pragma unroll
        for (int t = 0; t < NT; ++t) {
            float a = 0.f;
#pragma unroll
            for (int r = 0; r < 4; ++r) a = fmaf(qv[t][r], rs[r], a);
            facc[t] += a;
        }
    }
    __shared__ float f_s[K_CL];
    for (int i = tid; i < K_CL; i += TPB) f_s[i] = 0.f;
    __syncthreads();
#pragma unroll
    for (int t = 0; t < NT; ++t) {
        float a = facc[t];
        a += __shfl_xor(a, 16);
        a += __shfl_xor(a, 32);
        int col = t * 16 + c16;
        if (g == 0 && col < K_CL) atomicAdd(&f_s[col], a);
    }
    __syncthreads();
    for (int i = tid; i < K_CL; i += TPB) atomicAdd(&fg[i], f_s[i]);
}

// ---- dispatch 2: pass2 blocks [0,625) + persistent stream blocks [625, 625+NSTR) ----
__global__ void __launch_bounds__(TPB) k_d2(const f32x4* __restrict__ X,
                                            const f32x4* __restrict__ Xdec,
                                            const float* __restrict__ enc,
                                            const float* __restrict__ cen,
                                            const float* __restrict__ fg,
                                            double* __restrict__ dec_slots,
                                            double* __restrict__ kl_slots) {
    if (blockIdx.x >= NMF) {
        dec_stream(X, Xdec, dec_slots, blockIdx.x - NMF, SC_HALF);
        return;
    }
    LANE_IDS();
    const int p2id = blockIdx.x;
    float4 abuf[2][4];
    LOADS4(p2id, abuf[0]);
    PROLOGUE_B();
    float lfv[NT], rfv[NT];
#pragma unroll
    for (int t = 0; t < NT; ++t) {
        int col = t * 16 + c16;
        if (col < K_CL) {
            float fv = fg[col];
            lfv[t] = __logf(fv);
            rfv[t] = rcpf(fv);
        } else { lfv[t] = 0.f; rfv[t] = 0.f; }
    }
    float kl_local = 0.f;
#pragma unroll
    for (int j = 0; j < GPB; ++j) {
        if (j + 1 < GPB) LOADS4(p2id + (j + 1) * NMF, abuf[(j + 1) & 1]);
        GROUP_COMPUTE_FROM(abuf[j & 1]);
        float tac[4] = {0.f, 0.f, 0.f, 0.f};
        float Ap[4]  = {0.f, 0.f, 0.f, 0.f};
        float Bp[4]  = {0.f, 0.f, 0.f, 0.f};
#pragma unroll
        for (int t = 0; t < NT; ++t) {
#pragma unroll
            for (int r = 0; r < 4; ++r) {
                if (t == 6 && !v6) continue;      // masked col: q==0, avoid log(0)
                float q = qv[t][r] * rs[r];
                float pu = q * q * rfv[t];
                tac[r] += pu;
                Ap[r] = fmaf(pu, __logf(q), Ap[r]);
                Bp[r] = fmaf(pu, lfv[t], Bp[r]);
            }
        }
#pragma unroll
        for (int r = 0; r < 4; ++r) {
            tac[r] += __shfl_xor(tac[r], 1); tac[r] += __shfl_xor(tac[r], 2);
            tac[r] += __shfl_xor(tac[r], 4); tac[r] += __shfl_xor(tac[r], 8);
            Ap[r]  += __shfl_xor(Ap[r], 1);  Ap[r]  += __shfl_xor(Ap[r], 2);
            Ap[r]  += __shfl_xor(Ap[r], 4);  Ap[r]  += __shfl_xor(Ap[r], 8);
            Bp[r]  += __shfl_xor(Bp[r], 1);  Bp[r]  += __shfl_xor(Bp[r], 2);
            Bp[r]  += __shfl_xor(Bp[r], 4);  Bp[r]  += __shfl_xor(Bp[r], 8);
        }
        if (c16 == 0) {
#pragma unroll
            for (int r = 0; r < 4; ++r)
                kl_local += (Ap[r] - Bp[r]) * rcpf(tac[r]) - __logf(tac[r]);
        }
    }
    __shared__ float red[TPB];
    red[tid] = kl_local;
    __syncthreads();
    for (int off = TPB / 2; off > 0; off >>= 1) {
        if (tid < off) red[tid] += red[tid + off];
        __syncthreads();
    }
    if (tid == 0) atomicAdd(&kl_slots[p2id & (NSLOT - 1)], (double)red[0]);
}

__global__ void k_final(const double* __restrict__ dec_s,
                        const double* __restrict__ kl_s,
                        float* __restrict__ out) {
    int l = threadIdx.x;     // 64 threads = one wave
    double d = dec_s[l];
    double k = kl_s[l];
#pragma unroll
    for (int off = 32; off > 0; off >>= 1) {
        d += __shfl_xor(d, off);
        k += __shfl_xor(k, off);
    }
    if (l == 0)
        out[0] = (float)(d / ((double)N_ROWS * (double)D_IN) + 1000.0 * (k / (double)N_ROWS));
}

extern "C" void kernel_launch(void* const* d_in, const int* in_sizes, int n_in,
                              void* d_out, int out_size, void* d_ws, size_t ws_size,
                              hipStream_t stream) {
    (void)in_sizes; (void)n_in; (void)out_size; (void)ws_size;
    const float* X   = (const float*)d_in[0];
    const float* enc = (const float*)d_in[1];
    const float* dec = (const float*)d_in[2];
    const float* cen = (const float*)d_in[3];
    float* out = (float*)d_out;

    double* dec_slots = (double*)d_ws;                       // 64 doubles
    double* kl_slots  = (double*)((char*)d_ws + 512);        // 64 doubles
    float*  fg        = (float*)((char*)d_ws + 1024);        // 128 floats

    hipMemsetAsync(d_ws, 0, 1536, stream);
    k_d1<<<NMF + NSTR, TPB, 0, stream>>>(
        (const f32x4*)X, (const f32x4*)dec, enc, cen, dec_slots, fg);
    k_d2<<<NMF + NSTR, TPB, 0, stream>>>(
        (const f32x4*)X, (const f32x4*)dec, enc, cen, fg, dec_slots, kl_slots);
    k_final<<<1, 64, 0, stream>>>(dec_slots, kl_slots, out);
}